// Round 5
// baseline (12365.022 us; speedup 1.0000x reference)
//
#include <hip/hip_runtime.h>
#include <math.h>

#define HID    512
#define NIN    256
#define TIN    4096
#define NSTEP  1023
#define NEVAL  (NSTEP*4)
#define NWG    16
#define SLICE  32
#define NTH    1024
#define ETILE  64

// searchsorted(linspace(0,1,4096), t, side='left') clipped to [0, 4095]
__device__ __forceinline__ int zoh_index(float t) {
  const float delta = 1.0f / 4095.0f;
  int lo = 0, hi = TIN;
  while (lo < hi) {
    int mid = (lo + hi) >> 1;
    float g = (float)mid * delta;
    if (g < t) lo = mid + 1; else hi = mid;
  }
  return lo > TIN - 1 ? TIN - 1 : lo;
}

// Tiled gu precompute: gu[e][row] = U[row,:] @ I(t_e) + b[row], rows stacked [U_tau; U_f].
// Block (et, rb): 64 evals x 128 rows. I-tile staged once in LDS -> U traffic 4GB -> ~64MB.
__global__ void __launch_bounds__(256)
gu2_kernel(const float* __restrict__ I_seq, const float* __restrict__ t_save,
           const float* __restrict__ U_tau, const float* __restrict__ b_tau,
           const float* __restrict__ U_f,   const float* __restrict__ b_f,
           float* __restrict__ gu)
{
  __shared__ float Ild[ETILE][NIN];
  __shared__ int idxs[ETILE];
  const int tid = threadIdx.x;
  const int e0 = blockIdx.x * ETILE;
  const int rb = blockIdx.y;

  if (tid < ETILE) {
    const int e = e0 + tid;
    const int ec = e < NEVAL ? e : (NEVAL - 1);
    const int n = ec >> 2, s = ec & 3;
    const float t0 = t_save[n], t1 = t_save[n + 1];
    const float dt = t1 - t0;
    const float third = 1.0f / 3.0f;
    float t;
    if      (s == 0) t = t0;
    else if (s == 1) t = t0 + dt * third;
    else if (s == 2) t = t0 + (dt * 2.0f) * third;
    else             t = t1;
    idxs[tid] = zoh_index(t);
  }
  __syncthreads();
  #pragma unroll
  for (int q = 0; q < 16; ++q) {
    const int li = q * 256 + tid;      // 4096 float4 slots = 64 rows x 64
    const int ee = li >> 6, c4 = li & 63;
    ((float4*)&Ild[ee][0])[c4] = ((const float4*)(I_seq + (size_t)idxs[ee] * NIN))[c4];
  }
  __syncthreads();

  const int half = tid >> 7;                 // evals [32*half, +32)
  const int row  = rb * 128 + (tid & 127);   // 0..1023 stacked rows
  const float* Urow = (row < HID) ? (U_tau + (size_t)row * NIN)
                                  : (U_f + (size_t)(row - HID) * NIN);
  const float bb = (row < HID) ? b_tau[row] : b_f[row - HID];

  float acc[32];
  #pragma unroll
  for (int k = 0; k < 32; ++k) acc[k] = 0.f;

  #pragma unroll
  for (int c = 0; c < 8; ++c) {
    float4 u[8];
    #pragma unroll
    for (int j = 0; j < 8; ++j) u[j] = ((const float4*)Urow)[c * 8 + j];
    #pragma unroll
    for (int k = 0; k < 32; ++k) {
      const int ee = half * 32 + k;
      const float4* iv = (const float4*)&Ild[ee][c * 32];
      float a = acc[k];
      #pragma unroll
      for (int j = 0; j < 8; ++j) {
        float4 x = iv[j];
        a = fmaf(u[j].x, x.x, a); a = fmaf(u[j].y, x.y, a);
        a = fmaf(u[j].z, x.z, a); a = fmaf(u[j].w, x.w, a);
      }
      acc[k] = a;
    }
  }
  #pragma unroll
  for (int k = 0; k < 32; ++k) {
    const int e = e0 + half * 32 + k;
    if (e < NEVAL) gu[(size_t)e * 1024 + row] = acc[k] + bb;
  }
}

// Persistent cooperative scan, 16 WGs x 1024 threads (round-3-proven sync substrate:
// packed (tag,value) words, agent-scope relaxed atomics at the LLC, parity ping-pong).
// Lane map within each wave: lane = rr<<5 | m<<4 | seg  (rr: state-row pair bit,
// m: 0=tau/1=f matrix, seg: 16 column segments of 32). After the 4-level seg
// reduce, shfl_xor(.,16) swaps tau/f partials -> zt,zf in ONE lane: no pre[] LDS
// round-trip, ONE __syncthreads per eval.
__global__ void __launch_bounds__(NTH, 1)
ltc_main(const float* __restrict__ x0, const float* __restrict__ t_save,
         const float* __restrict__ W_tau, const float* __restrict__ tau0,
         const float* __restrict__ W_f,
         const float* __restrict__ gu,
         unsigned long long* xslot,          // [2][512] packed (tag, value)
         float* __restrict__ out)
{
  const int wg   = blockIdx.x;
  const int tid  = threadIdx.x;
  const int seg  = tid & 15;                 // column segment (32 cols)
  const int m    = (tid >> 4) & 1;           // 0 = tau row, 1 = f row
  const int r    = ((tid >> 6) << 1) | ((tid >> 5) & 1);  // 0..31 state in slice
  const int base = wg * SLICE;
  const int row  = base + r;

  const float* wrow = ((m == 0)
      ? (W_tau + (size_t)row * HID)
      : (W_f   + (size_t)row * HID)) + seg * 32;

  float4 w4[8];
  #pragma unroll
  for (int t = 0; t < 8; ++t) w4[t] = ((const float4*)wrow)[t];

  __shared__ float xsp[2][16][36];           // stride-36: <=2-way conflicts (free)

  const bool isP = (m == 0) && (seg == 0);   // producer lane for state `row`

  float y0 = 0.f, k1 = 0.f, k2 = 0.f, k3 = 0.f, curx = 0.f, tz = 0.f;
  if (isP) {
    y0   = x0[row];
    curx = y0;
    tz   = tau0[row];
    out[row] = y0;                           // out[0] = x0
  }

  // prefetch gu for eval 0
  float gtn = 0.f, gfn = 0.f;
  if (isP) {
    gtn = gu[row];
    gfn = gu[HID + row];
  }

  for (int n = 0; n < NSTEP; ++n) {
    const float dt = isP ? (t_save[n + 1] - t_save[n]) : 0.f;
    #pragma unroll
    for (int s = 0; s < 4; ++s) {
      const int e = (n << 2) + s;

      // ---- acquire x_e: threads 0..511 spin on their packed word, fill LDS ----
      if (tid < HID) {
        float v;
        if (e == 0) {
          v = x0[tid];
        } else {
          const unsigned long long* src = xslot + (size_t)(e & 1) * HID + tid;
          unsigned long long pk;
          do {
            pk = __hip_atomic_load(src, __ATOMIC_RELAXED, __HIP_MEMORY_SCOPE_AGENT);
          } while ((unsigned)(pk >> 32) != (unsigned)e);
          v = __uint_as_float((unsigned)pk);
        }
        xsp[e & 1][tid >> 5][tid & 31] = v;
      }
      __syncthreads();

      // rotate gu prefetch (current <- next), issue next eval's gu loads now:
      // their latency hides under matvec + next poll, never on the critical path
      const float gt = gtn, gf = gfn;
      if (isP && e + 1 < NEVAL) {
        gtn = gu[(size_t)(e + 1) * 1024 + row];
        gfn = gu[(size_t)(e + 1) * 1024 + HID + row];
      }

      // ---- matvec: 32 MACs/thread from VGPR weights + LDS x ----
      const float* xs = &xsp[e & 1][seg][0];
      float acc = 0.f;
      #pragma unroll
      for (int t = 0; t < 8; ++t) {
        const float4 xv = ((const float4*)xs)[t];
        acc = fmaf(w4[t].x, xv.x, acc);
        acc = fmaf(w4[t].y, xv.y, acc);
        acc = fmaf(w4[t].z, xv.z, acc);
        acc = fmaf(w4[t].w, xv.w, acc);
      }
      acc += __shfl_xor(acc, 1);
      acc += __shfl_xor(acc, 2);
      acc += __shfl_xor(acc, 4);
      acc += __shfl_xor(acc, 8);
      const float other = __shfl_xor(acc, 16);   // swap tau<->f partner row sums

      // ---- elementwise + RK4 update in-lane; packed store IS the release ----
      if (isP) {
        const float zt  = acc + gt;
        const float zf  = other + gf;
        const float ez  = __expf(-fabsf(zt));
        const float sp  = fmaxf(zt, 0.f) + __logf(1.f + ez);
        const float tau = tz + sp;
        const float ef  = __expf(-2.f * fabsf(zf));
        const float th  = (1.f - ef) / (1.f + ef);
        const float f   = (zf >= 0.f) ? th : -th;
        const float d   = f - curx / tau;
        float xnew;
        if      (s == 0) { k1 = d; xnew = y0 + dt * k1 * (1.0f/3.0f); }
        else if (s == 1) { k2 = d; xnew = y0 + dt * (k2 - k1 * (1.0f/3.0f)); }
        else if (s == 2) { k3 = d; xnew = y0 + dt * (k1 - k2 + k3); }
        else {
          xnew = y0 + (k1 + 3.0f * (k2 + k3) + d) * dt * 0.125f;
          y0 = xnew;
          out[(size_t)(n + 1) * HID + row] = xnew;
        }
        curx = xnew;
        const unsigned long long pk =
            ((unsigned long long)(unsigned)(e + 1) << 32) |
            (unsigned long long)__float_as_uint(xnew);
        __hip_atomic_store(xslot + (size_t)((e + 1) & 1) * HID + row, pk,
                           __ATOMIC_RELAXED, __HIP_MEMORY_SCOPE_AGENT);
      }
      // no trailing barrier: xsp is parity double-buffered; compute reads of
      // xsp[e&1] precede barrier(e+1) in program order, and staging writes to
      // xsp[e&1] for eval e+2 happen only after barrier(e+1).
    }
  }
}

extern "C" void kernel_launch(void* const* d_in, const int* in_sizes, int n_in,
                              void* d_out, int out_size, void* d_ws, size_t ws_size,
                              hipStream_t stream) {
  const float* x0     = (const float*)d_in[0];
  const float* I_seq  = (const float*)d_in[1];
  const float* t_save = (const float*)d_in[2];
  const float* W_tau  = (const float*)d_in[3];
  const float* U_tau  = (const float*)d_in[4];
  const float* b_tau  = (const float*)d_in[5];
  const float* tau0   = (const float*)d_in[6];
  const float* W_f    = (const float*)d_in[7];
  const float* U_f    = (const float*)d_in[8];
  const float* b_f    = (const float*)d_in[9];
  float* out = (float*)d_out;

  char* ws = (char*)d_ws;
  unsigned long long* xslot = (unsigned long long*)(ws + 1024);  // [2][512] = 8KB
  float* gu = (float*)(ws + 16384);                              // NEVAL*1024 floats (~16.8MB)

  // zero tags every call -> replay-safe, first-call-safe (tag 0 never matches)
  hipMemsetAsync(xslot, 0, 2 * HID * sizeof(unsigned long long), stream);
  gu2_kernel<<<dim3(64, 8), 256, 0, stream>>>(I_seq, t_save, U_tau, b_tau, U_f, b_f, gu);

  void* args[] = { (void*)&x0, (void*)&t_save, (void*)&W_tau, (void*)&tau0, (void*)&W_f,
                   (void*)&gu, (void*)&xslot, (void*)&out };
  hipLaunchCooperativeKernel((const void*)ltc_main, dim3(NWG), dim3(NTH),
                             args, 0, stream);
}

// Round 6
// 8332.182 us; speedup vs baseline: 1.4840x; 1.4840x over previous
//
#include <hip/hip_runtime.h>
#include <math.h>

#define HID    512
#define NIN    256
#define TIN    4096
#define NSTEP  1023
#define NEVAL  (NSTEP*4)
#define NWG    16
#define SLICE  32          // state elements owned per WG
#define NTH    1024
#define XPAD   16          // u64 stride per state word -> one 128B line each

// searchsorted(linspace(0,1,4096), t, side='left') clipped to [0, 4095]
__device__ __forceinline__ int zoh_index(float t) {
  const float delta = 1.0f / 4095.0f;
  int lo = 0, hi = TIN;
  while (lo < hi) {
    int mid = (lo + hi) >> 1;
    float g = (float)mid * delta;
    if (g < t) lo = mid + 1; else hi = mid;
  }
  return lo > TIN - 1 ? TIN - 1 : lo;
}

// Round-3-proven gu precompute (~0.3-0.5 ms, no spill):
// gu[e][0:512] = U_tau @ I(t_e) + b_tau ; gu[e][512:1024] = U_f @ I(t_e) + b_f
__global__ void __launch_bounds__(256)
gu_kernel(const float* __restrict__ I_seq, const float* __restrict__ t_save,
          const float* __restrict__ U_tau, const float* __restrict__ b_tau,
          const float* __restrict__ U_f,   const float* __restrict__ b_f,
          float* __restrict__ gu)
{
  __shared__ float Ish[NIN];
  const int e = blockIdx.x;
  const int tid = threadIdx.x;
  const int n = e >> 2, s = e & 3;
  const float t0 = t_save[n], t1 = t_save[n + 1];
  const float dt = t1 - t0;
  const float third = 1.0f / 3.0f;
  float t;
  if      (s == 0) t = t0;
  else if (s == 1) t = t0 + dt * third;
  else if (s == 2) t = t0 + (dt * 2.0f) * third;
  else             t = t1;
  const int idx = zoh_index(t);
  Ish[tid] = I_seq[idx * NIN + tid];
  __syncthreads();
  float* go = gu + (size_t)e * 1024;
  #pragma unroll
  for (int m = 0; m < 2; ++m) {
    const float* __restrict__ U = m ? U_f : U_tau;
    const float* __restrict__ b = m ? b_f : b_tau;
    #pragma unroll
    for (int hh = 0; hh < 2; ++hh) {
      const int h = tid + hh * 256;
      const float4* __restrict__ Ur = (const float4*)(U + (size_t)h * NIN);
      float acc = 0.f;
      #pragma unroll 8
      for (int k = 0; k < NIN / 4; ++k) {
        float4 u = Ur[k];
        acc = fmaf(u.x, Ish[4*k+0], acc);
        acc = fmaf(u.y, Ish[4*k+1], acc);
        acc = fmaf(u.z, Ish[4*k+2], acc);
        acc = fmaf(u.w, Ish[4*k+3], acc);
      }
      go[m * 512 + h] = acc + b[h];
    }
  }
}

// Persistent cooperative scan, 16 WGs x 1024 threads (round-3-proven structure).
// Sync is pure dataflow: packed (tag<<32 | float bits) words, agent-scope relaxed
// atomics at the LLC, parity ping-pong. ONLY change vs round 3: each state word
// occupies its own 128B LLC line (XPAD stride) -> 1 producer + 16 pollers per
// line instead of 16 producers + 256 pollers, de-serializing the release store.
__global__ void __launch_bounds__(NTH, 1)
ltc_main(const float* __restrict__ x0, const float* __restrict__ t_save,
         const float* __restrict__ W_tau, const float* __restrict__ tau0,
         const float* __restrict__ W_f,
         const float* __restrict__ gu,
         unsigned long long* xslot,          // [2][512][XPAD] packed (tag, value)
         float* __restrict__ out)
{
  const int wg   = blockIdx.x;
  const int tid  = threadIdx.x;
  const int row  = tid >> 4;    // 0..63
  const int seg  = tid & 15;    // 0..15, 32 columns each
  const int base = wg * SLICE;

  const float* wrow = ((row < SLICE)
      ? (W_tau + (size_t)(base + row) * HID)
      : (W_f   + (size_t)(base + row - SLICE) * HID)) + seg * 32;

  float4 w4[8];
  #pragma unroll
  for (int t = 0; t < 8; ++t) w4[t] = ((const float4*)wrow)[t];

  __shared__ float xsp[16 * 36];   // padded stride-36: <=2-way conflicts (free)
  __shared__ float pre[64];

  float y0 = 0.f, k1 = 0.f, k2 = 0.f, k3 = 0.f, curx = 0.f, tz = 0.f;
  if (tid < SLICE) {
    y0   = x0[base + tid];
    curx = y0;
    tz   = tau0[base + tid];
    out[base + tid] = y0;            // out[0] = x0
  }

  for (int n = 0; n < NSTEP; ++n) {
    const float t0 = t_save[n], t1 = t_save[n + 1];
    const float dt = t1 - t0;
    #pragma unroll
    for (int s = 0; s < 4; ++s) {
      const int e = (n << 2) + s;

      // gu loads issued first: latency hides under the spin below
      float gt = 0.f, gf = 0.f;
      if (tid < SLICE) {
        const float* g = gu + (size_t)e * 1024 + base + tid;
        gt = g[0];
        gf = g[512];
      }

      // ---- acquire x_e: spin on packed (tag,value) words, fill LDS ----
      if (tid < HID) {
        float v;
        if (e == 0) {
          v = x0[tid];
        } else {
          const unsigned long long* src =
              xslot + ((size_t)(e & 1) * HID + tid) * XPAD;
          unsigned long long pk;
          do {
            pk = __hip_atomic_load(src, __ATOMIC_RELAXED, __HIP_MEMORY_SCOPE_AGENT);
          } while ((unsigned)(pk >> 32) != (unsigned)e);
          v = __uint_as_float((unsigned)pk);
        }
        xsp[(tid >> 5) * 36 + (tid & 31)] = v;
      }
      __syncthreads();

      // ---- matvec: 32 MACs/thread from VGPR weights + LDS x ----
      float acc = 0.f;
      #pragma unroll
      for (int t = 0; t < 8; ++t) {
        const float4 xv = *reinterpret_cast<const float4*>(&xsp[seg * 36 + 4 * t]);
        acc = fmaf(w4[t].x, xv.x, acc);
        acc = fmaf(w4[t].y, xv.y, acc);
        acc = fmaf(w4[t].z, xv.z, acc);
        acc = fmaf(w4[t].w, xv.w, acc);
      }
      acc += __shfl_xor(acc, 1);
      acc += __shfl_xor(acc, 2);
      acc += __shfl_xor(acc, 4);
      acc += __shfl_xor(acc, 8);
      if ((tid & 15) == 0) pre[row] = acc;
      __syncthreads();

      // ---- elementwise + RK4 update; packed store IS the release ----
      if (tid < SLICE) {
        const float zt  = pre[tid] + gt;
        const float zf  = pre[SLICE + tid] + gf;
        const float ez  = __expf(-fabsf(zt));
        const float sp  = fmaxf(zt, 0.f) + __logf(1.f + ez);
        const float tau = tz + sp;
        const float ef  = __expf(-2.f * fabsf(zf));
        const float th  = (1.f - ef) / (1.f + ef);
        const float f   = (zf >= 0.f) ? th : -th;
        const float d   = f - curx / tau;
        float xnew;
        if      (s == 0) { k1 = d; xnew = y0 + dt * k1 * (1.0f/3.0f); }
        else if (s == 1) { k2 = d; xnew = y0 + dt * (k2 - k1 * (1.0f/3.0f)); }
        else if (s == 2) { k3 = d; xnew = y0 + dt * (k1 - k2 + k3); }
        else             { xnew = y0 + (k1 + 3.0f * (k2 + k3) + d) * dt * 0.125f; y0 = xnew; }
        curx = xnew;
        const unsigned long long pk =
            ((unsigned long long)(unsigned)(e + 1) << 32) |
            (unsigned long long)__float_as_uint(xnew);
        __hip_atomic_store(xslot + ((size_t)((e + 1) & 1) * HID + base + tid) * XPAD,
                           pk, __ATOMIC_RELAXED, __HIP_MEMORY_SCOPE_AGENT);
        if (s == 3) out[(size_t)(n + 1) * HID + base + tid] = xnew;  // after release
      }
      // no trailing syncthreads: ordered by the two barriers above (round-3 proven)
    }
  }
}

extern "C" void kernel_launch(void* const* d_in, const int* in_sizes, int n_in,
                              void* d_out, int out_size, void* d_ws, size_t ws_size,
                              hipStream_t stream) {
  const float* x0     = (const float*)d_in[0];
  const float* I_seq  = (const float*)d_in[1];
  const float* t_save = (const float*)d_in[2];
  const float* W_tau  = (const float*)d_in[3];
  const float* U_tau  = (const float*)d_in[4];
  const float* b_tau  = (const float*)d_in[5];
  const float* tau0   = (const float*)d_in[6];
  const float* W_f    = (const float*)d_in[7];
  const float* U_f    = (const float*)d_in[8];
  const float* b_f    = (const float*)d_in[9];
  float* out = (float*)d_out;

  char* ws = (char*)d_ws;
  unsigned long long* xslot = (unsigned long long*)(ws + 4096); // [2][512][16] u64 = 128KB
  float* gu = (float*)(ws + 4096 + 2 * HID * XPAD * sizeof(unsigned long long) + 4096);

  // zero tags every call -> replay-safe, first-call-safe (tag 0 never matches)
  hipMemsetAsync(xslot, 0, 2 * HID * XPAD * sizeof(unsigned long long), stream);
  gu_kernel<<<NEVAL, 256, 0, stream>>>(I_seq, t_save, U_tau, b_tau, U_f, b_f, gu);

  void* args[] = { (void*)&x0, (void*)&t_save, (void*)&W_tau, (void*)&tau0, (void*)&W_f,
                   (void*)&gu, (void*)&xslot, (void*)&out };
  hipLaunchCooperativeKernel((const void*)ltc_main, dim3(NWG), dim3(NTH),
                             args, 0, stream);
}